// Round 1
// baseline (789.166 us; speedup 1.0000x reference)
//
#include <hip/hip_runtime.h>

namespace {

constexpr int XS_LD = 264;   // bf16 elems per gathered-x row (256 + pad)
constexpr int WS_LD = 136;   // bf16 elems per w chunk row (128 + pad)
constexpr int QS_LD = 200;   // bf16 elems per q row (192 + pad)
constexpr int KT_LD = 72;    // bf16 elems per kT row (64 + pad)

constexpr int XS_BYTES = 64  * XS_LD * 2;   // 33792
constexpr int WS_BYTES = 256 * WS_LD * 2;   // 69632
constexpr int QS_BYTES = 64  * QS_LD * 2;   // 25600
constexpr int KT_BYTES = 192 * KT_LD * 2;   // 27648
constexpr int LDS_TOTAL = XS_BYTES + WS_BYTES + QS_BYTES + KT_BYTES + 64 * 4; // 156928
static_assert(LDS_TOTAL <= 160 * 1024, "LDS budget");

__device__ __forceinline__ float bflo(unsigned u) { return __uint_as_float(u << 16); }
__device__ __forceinline__ float bfhi(unsigned u) { return __uint_as_float(u & 0xffff0000u); }
__device__ __forceinline__ unsigned short f2bf(float f) {
  unsigned u = __float_as_uint(f);
  u += 0x7fffu + ((u >> 16) & 1u);          // round-to-nearest-even
  return (unsigned short)(u >> 16);
}
// element kk (0..7) of a uint4 holding 8 bf16; kk must be compile-time (unrolled)
__device__ __forceinline__ float bf16_elem(const uint4& v, int kk) {
  const unsigned w = (kk & 4) ? ((kk & 2) ? v.w : v.z) : ((kk & 2) ? v.y : v.x);
  return (kk & 1) ? bfhi(w) : bflo(w);
}

__global__ __launch_bounds__(256, 1)
void fused_mhaw(const float* __restrict__ x,
                const int*   __restrict__ reidx,
                const float* __restrict__ w_in,
                const float* __restrict__ b_in,
                const float* __restrict__ btab,     // [225][8]
                const int*   __restrict__ rpidx,    // [64][64]
                float*       __restrict__ out)      // [8][2][1024][64][64]
{
  extern __shared__ char lds[];
  unsigned short* xs = reinterpret_cast<unsigned short*>(lds);
  unsigned short* ws = reinterpret_cast<unsigned short*>(lds + XS_BYTES);
  unsigned short* qs = reinterpret_cast<unsigned short*>(lds + XS_BYTES + WS_BYTES);
  unsigned short* kT = reinterpret_cast<unsigned short*>(lds + XS_BYTES + WS_BYTES + QS_BYTES);
  int* srcbuf        = reinterpret_cast<int*>(lds + XS_BYTES + WS_BYTES + QS_BYTES + KT_BYTES);

  const int tid = threadIdx.x;
  const int b   = blockIdx.x >> 10;
  const int win = blockIdx.x & 1023;
  const int wh  = win >> 5, ww = win & 31;

  // ---- phase 0: gather indices for this window's 64 tokens -------------
  if (tid < 64) {
    const int r    = tid;
    const int trow = wh * 8 + (r >> 3);
    const int tcol = ww * 8 + (r & 7);
    srcbuf[r] = reidx[trow * 256 + tcol];
  }
  __syncthreads();

  // ---- phase 1: gather x rows (f32 -> bf16 into xs) ---------------------
  {
    const int r    = tid >> 2;       // 0..63
    const int part = tid & 3;        // contiguous quarter of the 256-f32 row
    const float* xrow = x + ((size_t)b * 65536 + (size_t)srcbuf[r]) * 256;
#pragma unroll
    for (int i = 0; i < 16; ++i) {
      const int c = part * 64 + i * 4;
      const float4 v = *reinterpret_cast<const float4*>(xrow + c);
      ushort4 u;
      u.x = f2bf(v.x); u.y = f2bf(v.y); u.z = f2bf(v.z); u.w = f2bf(v.w);
      *reinterpret_cast<ushort4*>(&xs[r * XS_LD + c]) = u;
    }
  }

  // ---- phase 2: projection GEMM, 3 chunks of 128 output cols -----------
  const int ry = tid >> 5;   // 0..7  -> rows ry*8 .. ry*8+7
  const int cx = tid & 31;   // 0..31 -> cols cx*4 .. cx*4+3 within chunk

  for (int ch = 0; ch < 3; ++ch) {
    {   // stage w_in[:, ch*128 : ch*128+128] -> ws (bf16, row-major)
      const int m  = tid & 31;       // float4 column group
      const int kk = tid >> 5;       // 0..7
      for (int p = 0; p < 32; ++p) {
        const int k = p * 8 + kk;
        const float4 v = *reinterpret_cast<const float4*>(
            w_in + (size_t)k * 384 + ch * 128 + m * 4);
        ushort4 u;
        u.x = f2bf(v.x); u.y = f2bf(v.y); u.z = f2bf(v.z); u.w = f2bf(v.w);
        *reinterpret_cast<ushort4*>(&ws[k * WS_LD + m * 4]) = u;
      }
    }
    __syncthreads();   // xs (ch==0) + ws ready

    float acc[8][4];
#pragma unroll
    for (int rr = 0; rr < 8; ++rr)
#pragma unroll
      for (int c = 0; c < 4; ++c) acc[rr][c] = 0.f;

    for (int k0 = 0; k0 < 256; k0 += 8) {
      uint4 xraw[8];
#pragma unroll
      for (int rr = 0; rr < 8; ++rr)
        xraw[rr] = *reinterpret_cast<const uint4*>(&xs[(ry * 8 + rr) * XS_LD + k0]);
      uint2 wraw[8];
#pragma unroll
      for (int kk = 0; kk < 8; ++kk)
        wraw[kk] = *reinterpret_cast<const uint2*>(&ws[(k0 + kk) * WS_LD + cx * 4]);
#pragma unroll
      for (int kk = 0; kk < 8; ++kk) {
        const float w0 = bflo(wraw[kk].x), w1 = bfhi(wraw[kk].x);
        const float w2 = bflo(wraw[kk].y), w3 = bfhi(wraw[kk].y);
#pragma unroll
        for (int rr = 0; rr < 8; ++rr) {
          const float xv = bf16_elem(xraw[rr], kk);
          acc[rr][0] = fmaf(xv, w0, acc[rr][0]);
          acc[rr][1] = fmaf(xv, w1, acc[rr][1]);
          acc[rr][2] = fmaf(xv, w2, acc[rr][2]);
          acc[rr][3] = fmaf(xv, w3, acc[rr][3]);
        }
      }
    }

    const int colbase = ch * 128 + cx * 4;          // global proj col
    const float4 bv = *reinterpret_cast<const float4*>(b_in + colbase);
    if (colbase < 192) {                            // query part -> qs row-major
#pragma unroll
      for (int rr = 0; rr < 8; ++rr) {
        ushort4 u;
        u.x = f2bf(acc[rr][0] + bv.x);
        u.y = f2bf(acc[rr][1] + bv.y);
        u.z = f2bf(acc[rr][2] + bv.z);
        u.w = f2bf(acc[rr][3] + bv.w);
        *reinterpret_cast<ushort4*>(&qs[(ry * 8 + rr) * QS_LD + colbase]) = u;
      }
    } else {                                        // key part -> kT transposed
      const int kc = colbase - 192;
#pragma unroll
      for (int rr = 0; rr < 8; ++rr) {
        const int row = ry * 8 + rr;
        kT[(kc + 0) * KT_LD + row] = f2bf(acc[rr][0] + bv.x);
        kT[(kc + 1) * KT_LD + row] = f2bf(acc[rr][1] + bv.y);
        kT[(kc + 2) * KT_LD + row] = f2bf(acc[rr][2] + bv.z);
        kT[(kc + 3) * KT_LD + row] = f2bf(acc[rr][3] + bv.w);
      }
    }
    __syncthreads();
  }

  // ---- phase 3: scores + bias + softmax ---------------------------------
  const int rg = tid >> 3;        // 0..31 -> rows rg*2, rg*2+1
  const int jg = tid & 7;         // cols jg*8 .. jg*8+7
  const int r0 = rg * 2;

  int ridx0[8], ridx1[8];
  {
    const int4 a0 = *reinterpret_cast<const int4*>(rpidx + (r0 + 0) * 64 + jg * 8);
    const int4 a1 = *reinterpret_cast<const int4*>(rpidx + (r0 + 0) * 64 + jg * 8 + 4);
    const int4 c0 = *reinterpret_cast<const int4*>(rpidx + (r0 + 1) * 64 + jg * 8);
    const int4 c1 = *reinterpret_cast<const int4*>(rpidx + (r0 + 1) * 64 + jg * 8 + 4);
    ridx0[0] = a0.x; ridx0[1] = a0.y; ridx0[2] = a0.z; ridx0[3] = a0.w;
    ridx0[4] = a1.x; ridx0[5] = a1.y; ridx0[6] = a1.z; ridx0[7] = a1.w;
    ridx1[0] = c0.x; ridx1[1] = c0.y; ridx1[2] = c0.z; ridx1[3] = c0.w;
    ridx1[4] = c1.x; ridx1[5] = c1.y; ridx1[6] = c1.z; ridx1[7] = c1.w;
  }

  for (int h = 0; h < 8; ++h) {
    float s0[8], s1[8];
#pragma unroll
    for (int jj = 0; jj < 8; ++jj) { s0[jj] = 0.f; s1[jj] = 0.f; }

#pragma unroll
    for (int g = 0; g < 3; ++g) {
      const uint4 qa = *reinterpret_cast<const uint4*>(&qs[(r0 + 0) * QS_LD + h * 24 + g * 8]);
      const uint4 qb = *reinterpret_cast<const uint4*>(&qs[(r0 + 1) * QS_LD + h * 24 + g * 8]);
#pragma unroll
      for (int dd = 0; dd < 8; ++dd) {
        const float q0 = bf16_elem(qa, dd);
        const float q1 = bf16_elem(qb, dd);
        const uint4 kv = *reinterpret_cast<const uint4*>(
            &kT[(h * 24 + g * 8 + dd) * KT_LD + jg * 8]);
        const float kf[8] = { bflo(kv.x), bfhi(kv.x), bflo(kv.y), bfhi(kv.y),
                              bflo(kv.z), bfhi(kv.z), bflo(kv.w), bfhi(kv.w) };
#pragma unroll
        for (int jj = 0; jj < 8; ++jj) {
          s0[jj] = fmaf(q0, kf[jj], s0[jj]);
          s1[jj] = fmaf(q1, kf[jj], s1[jj]);
        }
      }
    }

#pragma unroll
    for (int jj = 0; jj < 8; ++jj) {
      s0[jj] += btab[(ridx0[jj] << 3) + h];
      s1[jj] += btab[(ridx1[jj] << 3) + h];
    }

    float m0 = s0[0], m1 = s1[0];
#pragma unroll
    for (int jj = 1; jj < 8; ++jj) { m0 = fmaxf(m0, s0[jj]); m1 = fmaxf(m1, s1[jj]); }
    m0 = fmaxf(m0, __shfl_xor(m0, 1)); m1 = fmaxf(m1, __shfl_xor(m1, 1));
    m0 = fmaxf(m0, __shfl_xor(m0, 2)); m1 = fmaxf(m1, __shfl_xor(m1, 2));
    m0 = fmaxf(m0, __shfl_xor(m0, 4)); m1 = fmaxf(m1, __shfl_xor(m1, 4));

    float sum0 = 0.f, sum1 = 0.f;
#pragma unroll
    for (int jj = 0; jj < 8; ++jj) {
      s0[jj] = __expf(s0[jj] - m0); sum0 += s0[jj];
      s1[jj] = __expf(s1[jj] - m1); sum1 += s1[jj];
    }
    sum0 += __shfl_xor(sum0, 1); sum1 += __shfl_xor(sum1, 1);
    sum0 += __shfl_xor(sum0, 2); sum1 += __shfl_xor(sum1, 2);
    sum0 += __shfl_xor(sum0, 4); sum1 += __shfl_xor(sum1, 4);
    const float inv0 = 1.0f / sum0, inv1 = 1.0f / sum1;

    float* op = out + (((size_t)h * 2 + b) * 1024 + win) * 4096 + (size_t)r0 * 64 + jg * 8;
    float4 oa, ob;
    oa.x = s0[0] * inv0; oa.y = s0[1] * inv0; oa.z = s0[2] * inv0; oa.w = s0[3] * inv0;
    ob.x = s0[4] * inv0; ob.y = s0[5] * inv0; ob.z = s0[6] * inv0; ob.w = s0[7] * inv0;
    *reinterpret_cast<float4*>(op)     = oa;
    *reinterpret_cast<float4*>(op + 4) = ob;
    oa.x = s1[0] * inv1; oa.y = s1[1] * inv1; oa.z = s1[2] * inv1; oa.w = s1[3] * inv1;
    ob.x = s1[4] * inv1; ob.y = s1[5] * inv1; ob.z = s1[6] * inv1; ob.w = s1[7] * inv1;
    *reinterpret_cast<float4*>(op + 64)     = oa;
    *reinterpret_cast<float4*>(op + 64 + 4) = ob;
  }
}

} // namespace

extern "C" void kernel_launch(void* const* d_in, const int* in_sizes, int n_in,
                              void* d_out, int out_size, void* d_ws, size_t ws_size,
                              hipStream_t stream) {
  const float* x     = (const float*)d_in[0];
  const int*   reidx = (const int*)d_in[1];
  const float* w_in  = (const float*)d_in[2];
  const float* b_in  = (const float*)d_in[3];
  const float* btab  = (const float*)d_in[4];
  const int*   rpidx = (const int*)d_in[5];
  float* out = (float*)d_out;

  dim3 grid(2048), block(256);
  fused_mhaw<<<grid, block, LDS_TOTAL, stream>>>(x, reidx, w_in, b_in, btab, rpidx, out);
}

// Round 2
// 144.543 us; speedup vs baseline: 5.4597x; 5.4597x over previous
//
#include <hip/hip_runtime.h>

namespace {

typedef __attribute__((ext_vector_type(4))) float f32x4;
typedef __attribute__((ext_vector_type(8))) short bf16x8;

constexpr int WFRAG_ELEMS = 24 * 8 * 64 * 8;          // 98304 bf16
constexpr int WFRAG_BYTES = WFRAG_ELEMS * 2;          // 196608
constexpr int BIAS_ELEMS  = 8 * 64 * 64;              // 32768 f32
constexpr size_t WS_NEEDED = (size_t)WFRAG_BYTES + (size_t)BIAS_ELEMS * 4;  // 327680

// LDS layout (bytes)
constexpr int TOK_OFF = 0;                 // 64 ints
constexpr int XS_OFF  = 256;               // [4 m][4 kkl][64 lane][8] bf16 = 16384
constexpr int CB_OFF  = 256 + 16384;       // 64 x 384 bf16, XOR-swizzled = 49152
constexpr int LDS_TOTAL = CB_OFF + 49152;  // 65792 -> 2 blocks/CU

__device__ __forceinline__ unsigned short f2bf(float f) {
  unsigned u = __float_as_uint(f);
  u += 0x7fffu + ((u >> 16) & 1u);   // RNE
  return (unsigned short)(u >> 16);
}

// byte offset of C[row][col] (bf16) with 16B-slot XOR swizzle
__device__ __forceinline__ int cb_addr(int row, int col) {
  const int slot = (col >> 3) ^ (row & 7);
  return CB_OFF + row * 768 + (slot << 4) + ((col & 7) << 1);
}

__global__ void prep(const float* __restrict__ w_in,
                     const float* __restrict__ btab,
                     const int*   __restrict__ rpidx,
                     unsigned short* __restrict__ wfrag,
                     float* __restrict__ biasx) {
  const int t = blockIdx.x * 256 + threadIdx.x;
  if (t < WFRAG_ELEMS) {
    const int j    = t & 7;
    const int lane = (t >> 3) & 63;
    const int kk   = (t >> 9) & 7;
    const int nt   = t >> 12;
    const int k    = kk * 32 + (lane >> 4) * 8 + j;
    const int col  = nt * 16 + (lane & 15);
    wfrag[t] = f2bf(w_in[k * 384 + col]);
  } else if (t < WFRAG_ELEMS + BIAS_ELEMS) {
    const int o = t - WFRAG_ELEMS;
    const int j = o & 63, i = (o >> 6) & 63, h = o >> 12;
    biasx[o] = btab[rpidx[i * 64 + j] * 8 + h];
  }
}

template <bool USE_WS>
__global__ __launch_bounds__(256, 2)
void fused_mhaw(const float* __restrict__ x,
                const int*   __restrict__ reidx,
                const float* __restrict__ w_in,
                const float* __restrict__ b_in,
                const float* __restrict__ btab,
                const int*   __restrict__ rpidx,
                const unsigned short* __restrict__ wfrag,
                const float* __restrict__ biasx,
                float*       __restrict__ out) {
  extern __shared__ char lds[];
  int* tok           = reinterpret_cast<int*>(lds + TOK_OFF);
  unsigned short* xs = reinterpret_cast<unsigned short*>(lds + XS_OFF);

  const int tid  = threadIdx.x;
  const int b    = blockIdx.x >> 10;
  const int win  = blockIdx.x & 1023;
  const int wh   = win >> 5, ww = win & 31;
  const int wave = tid >> 6, lane = tid & 63;
  const int l15  = lane & 15, q = lane >> 4;

  if (tid < 64)
    tok[tid] = reidx[(wh * 8 + (tid >> 3)) * 256 + ww * 8 + (tid & 7)];
  __syncthreads();

  // ---------------- projection: C[64][384] = X[64][256] * W ----------------
  f32x4 acc[6][4];
#pragma unroll
  for (int n = 0; n < 6; ++n)
#pragma unroll
    for (int m = 0; m < 4; ++m) acc[n][m] = (f32x4){0.f, 0.f, 0.f, 0.f};

  const int srow = tid >> 2;       // token row this thread stages
  const int part = tid & 3;        // 32-float chunk within the K-half
  const int sm_t = srow >> 4, sr15 = srow & 15;

  for (int hf = 0; hf < 2; ++hf) {
    if (hf) __syncthreads();       // all waves done with previous half
    {
      const float* xr = x + ((size_t)b * 65536 + (size_t)tok[srow]) * 256 + hf * 128 + part * 32;
      unsigned short* xd = xs + ((sm_t * 4 + part) * 64 + sr15) * 8;
#pragma unroll
      for (int g = 0; g < 4; ++g) {
        const float4 v0 = *reinterpret_cast<const float4*>(xr + g * 8);
        const float4 v1 = *reinterpret_cast<const float4*>(xr + g * 8 + 4);
        bf16x8 u;
        u[0] = (short)f2bf(v0.x); u[1] = (short)f2bf(v0.y);
        u[2] = (short)f2bf(v0.z); u[3] = (short)f2bf(v0.w);
        u[4] = (short)f2bf(v1.x); u[5] = (short)f2bf(v1.y);
        u[6] = (short)f2bf(v1.z); u[7] = (short)f2bf(v1.w);
        *reinterpret_cast<bf16x8*>(xd + g * 128) = u;
      }
    }
    __syncthreads();

#pragma unroll
    for (int kkl = 0; kkl < 4; ++kkl) {
      bf16x8 af[4];
#pragma unroll
      for (int m = 0; m < 4; ++m)
        af[m] = *reinterpret_cast<const bf16x8*>(xs + ((m * 4 + kkl) * 64 + lane) * 8);
      const int kk = hf * 4 + kkl;
#pragma unroll
      for (int n = 0; n < 6; ++n) {
        bf16x8 bfr;
        if (USE_WS) {
          bfr = *reinterpret_cast<const bf16x8*>(
              wfrag + (((wave * 6 + n) * 8 + kk) * 64 + lane) * 8);
        } else {
          const int colg = wave * 96 + n * 16 + l15;
#pragma unroll
          for (int jj = 0; jj < 8; ++jj)
            bfr[jj] = (short)f2bf(w_in[(kk * 32 + q * 8 + jj) * 384 + colg]);
        }
#pragma unroll
        for (int m = 0; m < 4; ++m)
          acc[n][m] = __builtin_amdgcn_mfma_f32_16x16x32_bf16(af[m], bfr, acc[n][m], 0, 0, 0);
      }
    }
  }

  // write C (+bias) to swizzled LDS buffer as bf16
#pragma unroll
  for (int n = 0; n < 6; ++n) {
    const int colg = wave * 96 + n * 16 + l15;
    const float bv = b_in[colg];
#pragma unroll
    for (int m = 0; m < 4; ++m)
#pragma unroll
      for (int r = 0; r < 4; ++r) {
        const int row = m * 16 + q * 4 + r;
        *reinterpret_cast<unsigned short*>(lds + cb_addr(row, colg)) =
            f2bf(acc[n][m][r] + bv);
      }
  }
  __syncthreads();

  // ---------------- per-head QK^T + bias + softmax -------------------------
  const bf16x8 vz = {0, 0, 0, 0, 0, 0, 0, 0};
  const f32x4 cz = {0.f, 0.f, 0.f, 0.f};

  for (int hh = 0; hh < 2; ++hh) {
    const int h = wave * 2 + hh;

    bf16x8 aq[4], bk[4];
#pragma unroll
    for (int mi = 0; mi < 4; ++mi)
      aq[mi] = (lane < 48)
                   ? *reinterpret_cast<const bf16x8*>(lds + cb_addr(mi * 16 + l15, h * 24 + q * 8))
                   : vz;
#pragma unroll
    for (int ni = 0; ni < 4; ++ni)
      bk[ni] = (lane < 48)
                   ? *reinterpret_cast<const bf16x8*>(lds + cb_addr(ni * 16 + l15, 192 + h * 24 + q * 8))
                   : vz;

    f32x4 s[4][4];
#pragma unroll
    for (int mi = 0; mi < 4; ++mi)
#pragma unroll
      for (int ni = 0; ni < 4; ++ni)
        s[mi][ni] = __builtin_amdgcn_mfma_f32_16x16x32_bf16(aq[mi], bk[ni], cz, 0, 0, 0);

    const size_t obase = (((size_t)h * 2 + b) * 1024 + win) * 4096;

#pragma unroll
    for (int mi = 0; mi < 4; ++mi) {
#pragma unroll
      for (int r = 0; r < 4; ++r) {
        const int i = mi * 16 + q * 4 + r;
        float v0, v1, v2, v3;
        if (USE_WS) {
          const float* bp = biasx + (size_t)(h * 64 + i) * 64 + l15;
          v0 = s[mi][0][r] + bp[0];
          v1 = s[mi][1][r] + bp[16];
          v2 = s[mi][2][r] + bp[32];
          v3 = s[mi][3][r] + bp[48];
        } else {
          v0 = s[mi][0][r] + btab[rpidx[i * 64 + 0  + l15] * 8 + h];
          v1 = s[mi][1][r] + btab[rpidx[i * 64 + 16 + l15] * 8 + h];
          v2 = s[mi][2][r] + btab[rpidx[i * 64 + 32 + l15] * 8 + h];
          v3 = s[mi][3][r] + btab[rpidx[i * 64 + 48 + l15] * 8 + h];
        }
        float mx = fmaxf(fmaxf(v0, v1), fmaxf(v2, v3));
        mx = fmaxf(mx, __shfl_xor(mx, 1));
        mx = fmaxf(mx, __shfl_xor(mx, 2));
        mx = fmaxf(mx, __shfl_xor(mx, 4));
        mx = fmaxf(mx, __shfl_xor(mx, 8));
        v0 = __expf(v0 - mx); v1 = __expf(v1 - mx);
        v2 = __expf(v2 - mx); v3 = __expf(v3 - mx);
        float sm = v0 + v1 + v2 + v3;
        sm += __shfl_xor(sm, 1);
        sm += __shfl_xor(sm, 2);
        sm += __shfl_xor(sm, 4);
        sm += __shfl_xor(sm, 8);
        const float inv = __builtin_amdgcn_rcpf(sm);
        float* op = out + obase + (size_t)i * 64 + l15;
        op[0]  = v0 * inv;
        op[16] = v1 * inv;
        op[32] = v2 * inv;
        op[48] = v3 * inv;
      }
    }
  }
}

}  // namespace

extern "C" void kernel_launch(void* const* d_in, const int* in_sizes, int n_in,
                              void* d_out, int out_size, void* d_ws, size_t ws_size,
                              hipStream_t stream) {
  const float* x     = (const float*)d_in[0];
  const int*   reidx = (const int*)d_in[1];
  const float* w_in  = (const float*)d_in[2];
  const float* b_in  = (const float*)d_in[3];
  const float* btab  = (const float*)d_in[4];
  const int*   rpidx = (const int*)d_in[5];
  float* out = (float*)d_out;

  const bool use_ws = ws_size >= WS_NEEDED;
  unsigned short* wfrag = (unsigned short*)d_ws;
  float* biasx = (float*)((char*)d_ws + WFRAG_BYTES);

  if (use_ws) {
    prep<<<dim3((WFRAG_ELEMS + BIAS_ELEMS + 255) / 256), dim3(256), 0, stream>>>(
        w_in, btab, rpidx, wfrag, biasx);
    fused_mhaw<true><<<dim3(2048), dim3(256), LDS_TOTAL, stream>>>(
        x, reidx, w_in, b_in, btab, rpidx, wfrag, biasx, out);
  } else {
    fused_mhaw<false><<<dim3(2048), dim3(256), LDS_TOTAL, stream>>>(
        x, reidx, w_in, b_in, btab, rpidx, nullptr, nullptr, out);
  }
}